// Round 1
// baseline (1190.071 us; speedup 1.0000x reference)
//
#include <hip/hip_runtime.h>
#include <hip/hip_bf16.h>

#define NT 16384
#define HID 1024
#define FFN_ 256
#define NE 12
#define TOPK 3

typedef float  float4x  __attribute__((ext_vector_type(4)));
typedef short  short8x  __attribute__((ext_vector_type(8)));

__device__ __forceinline__ unsigned short f2bf(float f) {
    unsigned u = __float_as_uint(f);
    u += 0x7fffu + ((u >> 16) & 1u);
    return (unsigned short)(u >> 16);
}

__device__ __forceinline__ void gl2lds16(const void* g, void* l) {
    __builtin_amdgcn_global_load_lds(
        (const __attribute__((address_space(1))) unsigned int*)g,
        (__attribute__((address_space(3))) unsigned int*)l, 16, 0, 0);
}

// ---------------- weight fp32 -> bf16 ----------------
__global__ __launch_bounds__(256) void cvt_weights(
    const float* __restrict__ w1, const float* __restrict__ w3, const float* __restrict__ w2,
    unsigned short* __restrict__ o1, unsigned short* __restrict__ o3, unsigned short* __restrict__ o2)
{
    const float* s; unsigned short* d;
    if (blockIdx.y == 0)      { s = w1; d = o1; }
    else if (blockIdx.y == 1) { s = w3; d = o3; }
    else                      { s = w2; d = o2; }
    const int n4 = NE * FFN_ * HID / 4;
    for (int i = blockIdx.x * blockDim.x + threadIdx.x; i < n4; i += gridDim.x * blockDim.x) {
        float4 v = ((const float4*)s)[i];
        ushort4 o;
        o.x = f2bf(v.x); o.y = f2bf(v.y); o.z = f2bf(v.z); o.w = f2bf(v.w);
        ((ushort4*)d)[i] = o;
    }
}

// ---------------- router: logits, top3, combine weights, x->bf16 ----------------
__global__ __launch_bounds__(256) void router_kernel(
    const float* __restrict__ X, const float* __restrict__ G,
    float* __restrict__ out_logits, float* __restrict__ out_sel,
    unsigned short* __restrict__ xb,
    int* __restrict__ sel_e, float* __restrict__ sel_w,
    int* __restrict__ counts, float* __restrict__ importance)
{
    __shared__ __align__(16) float gls[NE * HID];   // 48 KB
    for (int i = threadIdx.x; i < NE * HID / 4; i += 256)
        ((float4*)gls)[i] = ((const float4*)G)[i];
    __syncthreads();

    const int wave = threadIdx.x >> 6, lane = threadIdx.x & 63;
    const int t = blockIdx.x * 4 + wave;

    // each lane owns elements j*256 + lane*4 .. +3  (j=0..3)
    float xr[16];
    const float* xt = X + (size_t)t * HID;
    unsigned short* xbt = xb + (size_t)t * HID;
#pragma unroll
    for (int j = 0; j < 4; j++) {
        float4 v = ((const float4*)xt)[j * 64 + lane];
        xr[j*4+0] = v.x; xr[j*4+1] = v.y; xr[j*4+2] = v.z; xr[j*4+3] = v.w;
        ushort4 o;
        o.x = f2bf(v.x); o.y = f2bf(v.y); o.z = f2bf(v.z); o.w = f2bf(v.w);
        ((ushort4*)xbt)[j * 64 + lane] = o;
    }

    float logit[NE];
#pragma unroll
    for (int e = 0; e < NE; e++) {
        float s = 0.f;
#pragma unroll
        for (int j = 0; j < 4; j++) {
            float4 g = ((const float4*)gls)[e * 256 + j * 64 + lane];
            s += xr[j*4+0]*g.x + xr[j*4+1]*g.y + xr[j*4+2]*g.z + xr[j*4+3]*g.w;
        }
#pragma unroll
        for (int d = 32; d; d >>= 1) s += __shfl_xor(s, d, 64);
        logit[e] = s;
    }

    if (lane == 0) {
        float m = logit[0];
#pragma unroll
        for (int e = 1; e < NE; e++) m = fmaxf(m, logit[e]);
#pragma unroll
        for (int e = 0; e < NE; e++) out_logits[(size_t)t * NE + e] = logit[e];

        // top-3 by logit (== top-3 by softmax), lowest index wins ties
        bool used[NE];
#pragma unroll
        for (int e = 0; e < NE; e++) used[e] = false;
        int   sel[TOPK];
        float w[TOPK];
        float wsum = 0.f;
#pragma unroll
        for (int k = 0; k < TOPK; k++) {
            int best = -1; float bv = -1e30f;
            for (int e = 0; e < NE; e++)
                if (!used[e] && logit[e] > bv) { bv = logit[e]; best = e; }
            used[best] = true;
            sel[k] = best;
            w[k] = __expf(bv - m);
            wsum += w[k];
        }
        float inv = 1.f / wsum;
#pragma unroll
        for (int k = 0; k < TOPK; k++) {
            float wk = w[k] * inv;
            out_sel[(size_t)t * TOPK + k] = (float)sel[k];
            sel_e[t * TOPK + k] = sel[k];
            sel_w[t * TOPK + k] = wk;
            atomicAdd(&counts[sel[k]], 1);
            atomicAdd(&importance[sel[k]], wk);
        }
    }
}

// ---------------- prefix scan + router loss ----------------
__global__ void scan_loss(const int* __restrict__ counts, int* __restrict__ cursor,
                          int* __restrict__ offsets, const float* __restrict__ importance,
                          float* __restrict__ loss_out)
{
    if (threadIdx.x == 0) {
        int acc = 0;
        for (int e = 0; e < NE; e++) { offsets[e] = acc; cursor[e] = acc; acc += counts[e]; }
        offsets[NE] = acc;
        float mean = 0.f;
        for (int e = 0; e < NE; e++) mean += importance[e];
        mean /= (float)NE;
        float var = 0.f;
        for (int e = 0; e < NE; e++) { float d = importance[e] - mean; var += d * d; }
        var /= (float)(NE - 1);   // ddof=1
        *loss_out = sqrtf(var);
    }
}

// ---------------- placement: compact per-expert slot lists ----------------
__global__ __launch_bounds__(256) void place_kernel(
    const int* __restrict__ sel_e, const float* __restrict__ sel_w,
    int* __restrict__ cursor, int* __restrict__ tok_ids, float* __restrict__ slot_w)
{
    int t = blockIdx.x * blockDim.x + threadIdx.x;
    if (t < NT) {
#pragma unroll
        for (int k = 0; k < TOPK; k++) {
            int e = sel_e[t * TOPK + k];
            int pos = atomicAdd(&cursor[e], 1);
            tok_ids[pos] = t;
            slot_w[pos] = sel_w[t * TOPK + k];
        }
    }
}

// ---------------- FFN1: H = silu(Xg @ W1^T) * (Xg @ W3^T) * w  -> bf16 ----------------
// tile: 128 slots x 64 ffn, K=1024, BK=32. 4 waves as 2x2 (wave 64 rows x 32 cols).
__global__ __launch_bounds__(256) void ffn1_kernel(
    const unsigned short* __restrict__ xb, const unsigned short* __restrict__ wb1,
    const unsigned short* __restrict__ wb3, const int* __restrict__ offsets,
    const int* __restrict__ tok_ids, const float* __restrict__ slot_w,
    unsigned short* __restrict__ H)
{
    const int e = blockIdx.z;
    const int base = offsets[e];
    const int count = offsets[e + 1] - base;
    const int m0 = blockIdx.x * 128;
    if (m0 >= count) return;
    const int n0 = blockIdx.y * 64;

    __shared__ __align__(16) unsigned short As[128 * 32];
    __shared__ __align__(16) unsigned short B1s[64 * 32];
    __shared__ __align__(16) unsigned short B3s[64 * 32];
    __shared__ int   tids[128];
    __shared__ float wts[128];

    const int tid = threadIdx.x;
    if (tid < 128) {
        int s = m0 + tid;
        tids[tid] = (s < count) ? tok_ids[base + s] : 0;
        wts[tid]  = (s < count) ? slot_w[base + s] : 0.f;
    }
    __syncthreads();

    const int wave = tid >> 6, lane = tid & 63;
    const int wave_m = wave & 1, wave_n = wave >> 1;

    const int arow0 = wave * 32 + (lane >> 2);
    const int tok0 = tids[arow0];
    const int tok1 = tids[arow0 + 16];
    const int brow = wave * 16 + (lane >> 2);

    const unsigned short* asrc0 = xb + (size_t)tok0 * HID + (lane & 3) * 8;
    const unsigned short* asrc1 = xb + (size_t)tok1 * HID + (lane & 3) * 8;
    const unsigned short* b1p = wb1 + (size_t)(e * FFN_ + n0 + brow) * HID + (lane & 3) * 8;
    const unsigned short* b3p = wb3 + (size_t)(e * FFN_ + n0 + brow) * HID + (lane & 3) * 8;

    char* aDst0 = (char*)As  + (wave * 32) * 64;
    char* aDst1 = (char*)As  + (wave * 32 + 16) * 64;
    char* b1Dst = (char*)B1s + wave * 1024;
    char* b3Dst = (char*)B3s + wave * 1024;

    float4x acc1[4][2], acc3[4][2];
#pragma unroll
    for (int mi = 0; mi < 4; mi++)
#pragma unroll
        for (int ni = 0; ni < 2; ni++) {
            acc1[mi][ni] = (float4x){0.f, 0.f, 0.f, 0.f};
            acc3[mi][ni] = (float4x){0.f, 0.f, 0.f, 0.f};
        }

    for (int kk = 0; kk < HID / 32; kk++) {
        __syncthreads();
        gl2lds16(asrc0, aDst0);
        gl2lds16(asrc1, aDst1);
        gl2lds16(b1p, b1Dst);
        gl2lds16(b3p, b3Dst);
        __syncthreads();
        asrc0 += 32; asrc1 += 32; b1p += 32; b3p += 32;

        short8x a[4], b1f[2], b3f[2];
#pragma unroll
        for (int mi = 0; mi < 4; mi++)
            a[mi] = *(const short8x*)(As + (wave_m * 64 + mi * 16 + (lane & 15)) * 32 + (lane >> 4) * 8);
#pragma unroll
        for (int ni = 0; ni < 2; ni++) {
            b1f[ni] = *(const short8x*)(B1s + (wave_n * 32 + ni * 16 + (lane & 15)) * 32 + (lane >> 4) * 8);
            b3f[ni] = *(const short8x*)(B3s + (wave_n * 32 + ni * 16 + (lane & 15)) * 32 + (lane >> 4) * 8);
        }
#pragma unroll
        for (int mi = 0; mi < 4; mi++)
#pragma unroll
            for (int ni = 0; ni < 2; ni++) {
                acc1[mi][ni] = __builtin_amdgcn_mfma_f32_16x16x32_bf16(a[mi], b1f[ni], acc1[mi][ni], 0, 0, 0);
                acc3[mi][ni] = __builtin_amdgcn_mfma_f32_16x16x32_bf16(a[mi], b3f[ni], acc3[mi][ni], 0, 0, 0);
            }
    }

#pragma unroll
    for (int mi = 0; mi < 4; mi++)
#pragma unroll
        for (int ni = 0; ni < 2; ni++)
#pragma unroll
            for (int r = 0; r < 4; r++) {
                int ml = wave_m * 64 + mi * 16 + (lane >> 4) * 4 + r;
                int s = m0 + ml;
                if (s < count) {
                    float v1 = acc1[mi][ni][r];
                    float v3 = acc3[mi][ni][r];
                    float h = v1 * (1.f / (1.f + __expf(-v1))) * v3 * wts[ml];
                    int n = n0 + wave_n * 32 + ni * 16 + (lane & 15);
                    H[(size_t)(base + s) * FFN_ + n] = f2bf(h);
                }
            }
}

// ---------------- FFN2: final += H @ W2^T (atomic scatter) ----------------
// tile: 128 slots x 128 hid, K=256, BK=32. 4 waves as 2x2 (wave 64x64).
__global__ __launch_bounds__(256) void ffn2_kernel(
    const unsigned short* __restrict__ H, const unsigned short* __restrict__ wb2,
    const int* __restrict__ offsets, const int* __restrict__ tok_ids,
    float* __restrict__ final_out)
{
    const int e = blockIdx.z;
    const int base = offsets[e];
    const int count = offsets[e + 1] - base;
    const int m0 = blockIdx.x * 128;
    if (m0 >= count) return;
    const int n0 = blockIdx.y * 128;

    __shared__ __align__(16) unsigned short As[128 * 32];
    __shared__ __align__(16) unsigned short Bs[128 * 32];
    __shared__ int tids[128];

    const int tid = threadIdx.x;
    if (tid < 128) {
        int s = m0 + tid;
        tids[tid] = (s < count) ? tok_ids[base + s] : 0;
    }
    __syncthreads();

    const int wave = tid >> 6, lane = tid & 63;
    const int wave_m = wave & 1, wave_n = wave >> 1;

    const int row0 = wave * 32 + (lane >> 2);
    const unsigned short* a0 = H + (size_t)(base + m0 + row0) * FFN_ + (lane & 3) * 8;
    const unsigned short* a1 = H + (size_t)(base + m0 + row0 + 16) * FFN_ + (lane & 3) * 8;
    const unsigned short* b0 = wb2 + (size_t)(e * HID + n0 + row0) * FFN_ + (lane & 3) * 8;
    const unsigned short* b1 = wb2 + (size_t)(e * HID + n0 + row0 + 16) * FFN_ + (lane & 3) * 8;

    char* aD0 = (char*)As + (wave * 32) * 64;
    char* aD1 = (char*)As + (wave * 32 + 16) * 64;
    char* bD0 = (char*)Bs + (wave * 32) * 64;
    char* bD1 = (char*)Bs + (wave * 32 + 16) * 64;

    float4x acc[4][4];
#pragma unroll
    for (int mi = 0; mi < 4; mi++)
#pragma unroll
        for (int ni = 0; ni < 4; ni++) acc[mi][ni] = (float4x){0.f, 0.f, 0.f, 0.f};

    for (int kk = 0; kk < FFN_ / 32; kk++) {
        __syncthreads();
        gl2lds16(a0, aD0);
        gl2lds16(a1, aD1);
        gl2lds16(b0, bD0);
        gl2lds16(b1, bD1);
        __syncthreads();
        a0 += 32; a1 += 32; b0 += 32; b1 += 32;

        short8x af[4], bf[4];
#pragma unroll
        for (int mi = 0; mi < 4; mi++)
            af[mi] = *(const short8x*)(As + (wave_m * 64 + mi * 16 + (lane & 15)) * 32 + (lane >> 4) * 8);
#pragma unroll
        for (int ni = 0; ni < 4; ni++)
            bf[ni] = *(const short8x*)(Bs + (wave_n * 64 + ni * 16 + (lane & 15)) * 32 + (lane >> 4) * 8);
#pragma unroll
        for (int mi = 0; mi < 4; mi++)
#pragma unroll
            for (int ni = 0; ni < 4; ni++)
                acc[mi][ni] = __builtin_amdgcn_mfma_f32_16x16x32_bf16(af[mi], bf[ni], acc[mi][ni], 0, 0, 0);
    }

#pragma unroll
    for (int mi = 0; mi < 4; mi++)
#pragma unroll
        for (int ni = 0; ni < 4; ni++)
#pragma unroll
            for (int r = 0; r < 4; r++) {
                int ml = wave_m * 64 + mi * 16 + (lane >> 4) * 4 + r;
                int s = m0 + ml;
                if (s < count) {
                    int n = n0 + wave_n * 64 + ni * 16 + (lane & 15);
                    atomicAdd(final_out + (size_t)tids[ml] * HID + n, acc[mi][ni][r]);
                }
            }
}

extern "C" void kernel_launch(void* const* d_in, const int* in_sizes, int n_in,
                              void* d_out, int out_size, void* d_ws, size_t ws_size,
                              hipStream_t stream) {
    const float* X  = (const float*)d_in[0];
    const float* G  = (const float*)d_in[1];
    const float* w1 = (const float*)d_in[2];
    const float* w2 = (const float*)d_in[3];
    const float* w3 = (const float*)d_in[4];

    float* out = (float*)d_out;
    float* out_final  = out;
    float* out_logits = out + (size_t)NT * HID;                        // 16777216
    float* out_sel    = out_logits + (size_t)NT * NE;                  // +196608
    float* out_loss   = out_sel + (size_t)NT * TOPK;                   // +49152

    char* ws = (char*)d_ws;
    int*   counts     = (int*)(ws + 0);
    int*   cursor     = (int*)(ws + 64);
    int*   offsets    = (int*)(ws + 128);
    float* importance = (float*)(ws + 192);
    int*   sel_e   = (int*)(ws + 512);
    float* sel_w   = (float*)(ws + 197120);
    int*   tok_ids = (int*)(ws + 393728);
    float* slot_w  = (float*)(ws + 590336);
    unsigned short* wb1 = (unsigned short*)(ws + 786944);
    unsigned short* wb3 = (unsigned short*)(ws + 7078400);
    unsigned short* wb2 = (unsigned short*)(ws + 13369856);
    unsigned short* H   = (unsigned short*)(ws + 19661312);            // (49152+128) rows x 256 bf16

    // x_bf16 lives in the (currently dead) `final` region of d_out; it is
    // consumed by ffn1 and then erased by the memset before ffn2 writes final.
    unsigned short* xb = (unsigned short*)d_out;

    hipMemsetAsync(ws, 0, 256, stream);
    cvt_weights<<<dim3(1024, 3), 256, 0, stream>>>(w1, w3, w2, wb1, wb3, wb2);
    router_kernel<<<NT / 4, 256, 0, stream>>>(X, G, out_logits, out_sel, xb,
                                              sel_e, sel_w, counts, importance);
    scan_loss<<<1, 64, 0, stream>>>(counts, cursor, offsets, importance, out_loss);
    place_kernel<<<NT / 256, 256, 0, stream>>>(sel_e, sel_w, cursor, tok_ids, slot_w);
    ffn1_kernel<<<dim3(128, 4, NE), 256, 0, stream>>>(xb, wb1, wb3, offsets, tok_ids, slot_w, H);
    hipMemsetAsync(d_out, 0, (size_t)NT * HID * sizeof(float), stream);
    ffn2_kernel<<<dim3(128, 8, NE), 256, 0, stream>>>(H, wb2, offsets, tok_ids, out_final);
}

// Round 2
// 451.388 us; speedup vs baseline: 2.6365x; 2.6365x over previous
//
#include <hip/hip_runtime.h>
#include <hip/hip_bf16.h>

#define NT 16384
#define HID 1024
#define FFN_ 256
#define NE 12
#define TOPK 3

typedef float  float4x  __attribute__((ext_vector_type(4)));
typedef short  short8x  __attribute__((ext_vector_type(8)));

__device__ __forceinline__ unsigned short f2bf(float f) {
    unsigned u = __float_as_uint(f);
    u += 0x7fffu + ((u >> 16) & 1u);
    return (unsigned short)(u >> 16);
}

__device__ __forceinline__ void gl2lds16(const void* g, void* l) {
    __builtin_amdgcn_global_load_lds(
        (const __attribute__((address_space(1))) unsigned int*)g,
        (__attribute__((address_space(3))) unsigned int*)l, 16, 0, 0);
}

// ---------------- weight fp32 -> bf16 ----------------
__global__ __launch_bounds__(256) void cvt_weights(
    const float* __restrict__ w1, const float* __restrict__ w3, const float* __restrict__ w2,
    unsigned short* __restrict__ o1, unsigned short* __restrict__ o3, unsigned short* __restrict__ o2)
{
    const float* s; unsigned short* d;
    if (blockIdx.y == 0)      { s = w1; d = o1; }
    else if (blockIdx.y == 1) { s = w3; d = o3; }
    else                      { s = w2; d = o2; }
    const int n4 = NE * FFN_ * HID / 4;
    for (int i = blockIdx.x * blockDim.x + threadIdx.x; i < n4; i += gridDim.x * blockDim.x) {
        float4 v = ((const float4*)s)[i];
        ushort4 o;
        o.x = f2bf(v.x); o.y = f2bf(v.y); o.z = f2bf(v.z); o.w = f2bf(v.w);
        ((ushort4*)d)[i] = o;
    }
}

// ---------------- router: logits, top3, per-token weights, x->bf16 (NO atomics) ---------
__global__ __launch_bounds__(256) void router_kernel(
    const float* __restrict__ X, const float* __restrict__ G,
    float* __restrict__ out_logits, float* __restrict__ out_sel,
    unsigned short* __restrict__ xb,
    int* __restrict__ sel_e, float* __restrict__ sel_w)
{
    __shared__ __align__(16) float gls[NE * HID];   // 48 KB
    for (int i = threadIdx.x; i < NE * HID / 4; i += 256)
        ((float4*)gls)[i] = ((const float4*)G)[i];
    __syncthreads();

    const int wave = threadIdx.x >> 6, lane = threadIdx.x & 63;
    const int t = blockIdx.x * 4 + wave;

    float xr[16];
    const float* xt = X + (size_t)t * HID;
    unsigned short* xbt = xb + (size_t)t * HID;
#pragma unroll
    for (int j = 0; j < 4; j++) {
        float4 v = ((const float4*)xt)[j * 64 + lane];
        xr[j*4+0] = v.x; xr[j*4+1] = v.y; xr[j*4+2] = v.z; xr[j*4+3] = v.w;
        ushort4 o;
        o.x = f2bf(v.x); o.y = f2bf(v.y); o.z = f2bf(v.z); o.w = f2bf(v.w);
        ((ushort4*)xbt)[j * 64 + lane] = o;
    }

    float logit[NE];
#pragma unroll
    for (int e = 0; e < NE; e++) {
        float s = 0.f;
#pragma unroll
        for (int j = 0; j < 4; j++) {
            float4 g = ((const float4*)gls)[e * 256 + j * 64 + lane];
            s += xr[j*4+0]*g.x + xr[j*4+1]*g.y + xr[j*4+2]*g.z + xr[j*4+3]*g.w;
        }
#pragma unroll
        for (int d = 32; d; d >>= 1) s += __shfl_xor(s, d, 64);
        logit[e] = s;
    }

    if (lane == 0) {
        float m = logit[0];
#pragma unroll
        for (int e = 1; e < NE; e++) m = fmaxf(m, logit[e]);
#pragma unroll
        for (int e = 0; e < NE; e++) out_logits[(size_t)t * NE + e] = logit[e];

        bool used[NE];
#pragma unroll
        for (int e = 0; e < NE; e++) used[e] = false;
        int   sel[TOPK];
        float w[TOPK];
        float wsum = 0.f;
#pragma unroll
        for (int k = 0; k < TOPK; k++) {
            int best = -1; float bv = -1e30f;
            for (int e = 0; e < NE; e++)
                if (!used[e] && logit[e] > bv) { bv = logit[e]; best = e; }
            used[best] = true;
            sel[k] = best;
            w[k] = __expf(bv - m);
            wsum += w[k];
        }
        float inv = 1.f / wsum;
#pragma unroll
        for (int k = 0; k < TOPK; k++) {
            float wk = w[k] * inv;
            out_sel[(size_t)t * TOPK + k] = (float)sel[k];
            sel_e[t * TOPK + k] = sel[k];
            sel_w[t * TOPK + k] = wk;
        }
    }
}

// ---------------- histogram: counts + importance via LDS aggregation ----------------
// 64 blocks x 256 threads, 1 token per thread. 12*2 global atomics per block.
__global__ __launch_bounds__(256) void hist_kernel(
    const int* __restrict__ sel_e, const float* __restrict__ sel_w,
    int* __restrict__ counts, float* __restrict__ importance)
{
    __shared__ int   lcnt[NE];
    __shared__ float limp[NE];
    const int tid = threadIdx.x;
    if (tid < NE) { lcnt[tid] = 0; limp[tid] = 0.f; }
    __syncthreads();
    const int t = blockIdx.x * 256 + tid;
#pragma unroll
    for (int k = 0; k < TOPK; k++) {
        int e = sel_e[t * TOPK + k];
        atomicAdd(&lcnt[e], 1);
        atomicAdd(&limp[e], sel_w[t * TOPK + k]);
    }
    __syncthreads();
    if (tid < NE) {
        atomicAdd(&counts[tid], lcnt[tid]);
        atomicAdd(&importance[tid], limp[tid]);
    }
}

// ---------------- prefix scan + router loss ----------------
__global__ void scan_loss(const int* __restrict__ counts, int* __restrict__ cursor,
                          int* __restrict__ offsets, const float* __restrict__ importance,
                          float* __restrict__ loss_out)
{
    if (threadIdx.x == 0) {
        int acc = 0;
        for (int e = 0; e < NE; e++) { offsets[e] = acc; cursor[e] = acc; acc += counts[e]; }
        offsets[NE] = acc;
        float mean = 0.f;
        for (int e = 0; e < NE; e++) mean += importance[e];
        mean /= (float)NE;
        float var = 0.f;
        for (int e = 0; e < NE; e++) { float d = importance[e] - mean; var += d * d; }
        var /= (float)(NE - 1);   // ddof=1
        *loss_out = sqrtf(var);
    }
}

// ---------------- placement: block-aggregated cursor atomics ----------------
// 64 blocks x 256 threads, 1 token per thread. LDS rank + 12 cursor atomics/block.
__global__ __launch_bounds__(256) void place_kernel(
    const int* __restrict__ sel_e, const float* __restrict__ sel_w,
    int* __restrict__ cursor, int* __restrict__ tok_ids, float* __restrict__ slot_w)
{
    __shared__ int lcnt[NE];
    __shared__ int lbase[NE];
    const int tid = threadIdx.x;
    if (tid < NE) lcnt[tid] = 0;
    __syncthreads();
    const int t = blockIdx.x * 256 + tid;
    int e[TOPK], r[TOPK];
#pragma unroll
    for (int k = 0; k < TOPK; k++) {
        e[k] = sel_e[t * TOPK + k];
        r[k] = atomicAdd(&lcnt[e[k]], 1);
    }
    __syncthreads();
    if (tid < NE) lbase[tid] = atomicAdd(&cursor[tid], lcnt[tid]);
    __syncthreads();
#pragma unroll
    for (int k = 0; k < TOPK; k++) {
        int pos = lbase[e[k]] + r[k];
        tok_ids[pos] = t;
        slot_w[pos] = sel_w[t * TOPK + k];
    }
}

// ---------------- FFN1: H = silu(Xg @ W1^T) * (Xg @ W3^T) * w  -> bf16 ----------------
__global__ __launch_bounds__(256) void ffn1_kernel(
    const unsigned short* __restrict__ xb, const unsigned short* __restrict__ wb1,
    const unsigned short* __restrict__ wb3, const int* __restrict__ offsets,
    const int* __restrict__ tok_ids, const float* __restrict__ slot_w,
    unsigned short* __restrict__ H)
{
    const int e = blockIdx.z;
    const int base = offsets[e];
    const int count = offsets[e + 1] - base;
    const int m0 = blockIdx.x * 128;
    if (m0 >= count) return;
    const int n0 = blockIdx.y * 64;

    __shared__ __align__(16) unsigned short As[128 * 32];
    __shared__ __align__(16) unsigned short B1s[64 * 32];
    __shared__ __align__(16) unsigned short B3s[64 * 32];
    __shared__ int   tids[128];
    __shared__ float wts[128];

    const int tid = threadIdx.x;
    if (tid < 128) {
        int s = m0 + tid;
        tids[tid] = (s < count) ? tok_ids[base + s] : 0;
        wts[tid]  = (s < count) ? slot_w[base + s] : 0.f;
    }
    __syncthreads();

    const int wave = tid >> 6, lane = tid & 63;
    const int wave_m = wave & 1, wave_n = wave >> 1;

    const int arow0 = wave * 32 + (lane >> 2);
    const int tok0 = tids[arow0];
    const int tok1 = tids[arow0 + 16];
    const int brow = wave * 16 + (lane >> 2);

    const unsigned short* asrc0 = xb + (size_t)tok0 * HID + (lane & 3) * 8;
    const unsigned short* asrc1 = xb + (size_t)tok1 * HID + (lane & 3) * 8;
    const unsigned short* b1p = wb1 + (size_t)(e * FFN_ + n0 + brow) * HID + (lane & 3) * 8;
    const unsigned short* b3p = wb3 + (size_t)(e * FFN_ + n0 + brow) * HID + (lane & 3) * 8;

    char* aDst0 = (char*)As  + (wave * 32) * 64;
    char* aDst1 = (char*)As  + (wave * 32 + 16) * 64;
    char* b1Dst = (char*)B1s + wave * 1024;
    char* b3Dst = (char*)B3s + wave * 1024;

    float4x acc1[4][2], acc3[4][2];
#pragma unroll
    for (int mi = 0; mi < 4; mi++)
#pragma unroll
        for (int ni = 0; ni < 2; ni++) {
            acc1[mi][ni] = (float4x){0.f, 0.f, 0.f, 0.f};
            acc3[mi][ni] = (float4x){0.f, 0.f, 0.f, 0.f};
        }

    for (int kk = 0; kk < HID / 32; kk++) {
        __syncthreads();
        gl2lds16(asrc0, aDst0);
        gl2lds16(asrc1, aDst1);
        gl2lds16(b1p, b1Dst);
        gl2lds16(b3p, b3Dst);
        __syncthreads();
        asrc0 += 32; asrc1 += 32; b1p += 32; b3p += 32;

        short8x a[4], b1f[2], b3f[2];
#pragma unroll
        for (int mi = 0; mi < 4; mi++)
            a[mi] = *(const short8x*)(As + (wave_m * 64 + mi * 16 + (lane & 15)) * 32 + (lane >> 4) * 8);
#pragma unroll
        for (int ni = 0; ni < 2; ni++) {
            b1f[ni] = *(const short8x*)(B1s + (wave_n * 32 + ni * 16 + (lane & 15)) * 32 + (lane >> 4) * 8);
            b3f[ni] = *(const short8x*)(B3s + (wave_n * 32 + ni * 16 + (lane & 15)) * 32 + (lane >> 4) * 8);
        }
#pragma unroll
        for (int mi = 0; mi < 4; mi++)
#pragma unroll
            for (int ni = 0; ni < 2; ni++) {
                acc1[mi][ni] = __builtin_amdgcn_mfma_f32_16x16x32_bf16(a[mi], b1f[ni], acc1[mi][ni], 0, 0, 0);
                acc3[mi][ni] = __builtin_amdgcn_mfma_f32_16x16x32_bf16(a[mi], b3f[ni], acc3[mi][ni], 0, 0, 0);
            }
    }

#pragma unroll
    for (int mi = 0; mi < 4; mi++)
#pragma unroll
        for (int ni = 0; ni < 2; ni++)
#pragma unroll
            for (int r = 0; r < 4; r++) {
                int ml = wave_m * 64 + mi * 16 + (lane >> 4) * 4 + r;
                int s = m0 + ml;
                if (s < count) {
                    float v1 = acc1[mi][ni][r];
                    float v3 = acc3[mi][ni][r];
                    float h = v1 * (1.f / (1.f + __expf(-v1))) * v3 * wts[ml];
                    int n = n0 + wave_n * 32 + ni * 16 + (lane & 15);
                    H[(size_t)(base + s) * FFN_ + n] = f2bf(h);
                }
            }
}

// ---------------- FFN2: final += H @ W2^T (atomic scatter) ----------------
__global__ __launch_bounds__(256) void ffn2_kernel(
    const unsigned short* __restrict__ H, const unsigned short* __restrict__ wb2,
    const int* __restrict__ offsets, const int* __restrict__ tok_ids,
    float* __restrict__ final_out)
{
    const int e = blockIdx.z;
    const int base = offsets[e];
    const int count = offsets[e + 1] - base;
    const int m0 = blockIdx.x * 128;
    if (m0 >= count) return;
    const int n0 = blockIdx.y * 128;

    __shared__ __align__(16) unsigned short As[128 * 32];
    __shared__ __align__(16) unsigned short Bs[128 * 32];
    __shared__ int tids[128];

    const int tid = threadIdx.x;
    if (tid < 128) {
        int s = m0 + tid;
        tids[tid] = (s < count) ? tok_ids[base + s] : 0;
    }
    __syncthreads();

    const int wave = tid >> 6, lane = tid & 63;
    const int wave_m = wave & 1, wave_n = wave >> 1;

    const int row0 = wave * 32 + (lane >> 2);
    const unsigned short* a0 = H + (size_t)(base + m0 + row0) * FFN_ + (lane & 3) * 8;
    const unsigned short* a1 = H + (size_t)(base + m0 + row0 + 16) * FFN_ + (lane & 3) * 8;
    const unsigned short* b0 = wb2 + (size_t)(e * HID + n0 + row0) * FFN_ + (lane & 3) * 8;
    const unsigned short* b1 = wb2 + (size_t)(e * HID + n0 + row0 + 16) * FFN_ + (lane & 3) * 8;

    char* aD0 = (char*)As + (wave * 32) * 64;
    char* aD1 = (char*)As + (wave * 32 + 16) * 64;
    char* bD0 = (char*)Bs + (wave * 32) * 64;
    char* bD1 = (char*)Bs + (wave * 32 + 16) * 64;

    float4x acc[4][4];
#pragma unroll
    for (int mi = 0; mi < 4; mi++)
#pragma unroll
        for (int ni = 0; ni < 4; ni++) acc[mi][ni] = (float4x){0.f, 0.f, 0.f, 0.f};

    for (int kk = 0; kk < FFN_ / 32; kk++) {
        __syncthreads();
        gl2lds16(a0, aD0);
        gl2lds16(a1, aD1);
        gl2lds16(b0, bD0);
        gl2lds16(b1, bD1);
        __syncthreads();
        a0 += 32; a1 += 32; b0 += 32; b1 += 32;

        short8x af[4], bf[4];
#pragma unroll
        for (int mi = 0; mi < 4; mi++)
            af[mi] = *(const short8x*)(As + (wave_m * 64 + mi * 16 + (lane & 15)) * 32 + (lane >> 4) * 8);
#pragma unroll
        for (int ni = 0; ni < 4; ni++)
            bf[ni] = *(const short8x*)(Bs + (wave_n * 64 + ni * 16 + (lane & 15)) * 32 + (lane >> 4) * 8);
#pragma unroll
        for (int mi = 0; mi < 4; mi++)
#pragma unroll
            for (int ni = 0; ni < 4; ni++)
                acc[mi][ni] = __builtin_amdgcn_mfma_f32_16x16x32_bf16(af[mi], bf[ni], acc[mi][ni], 0, 0, 0);
    }

#pragma unroll
    for (int mi = 0; mi < 4; mi++)
#pragma unroll
        for (int ni = 0; ni < 4; ni++)
#pragma unroll
            for (int r = 0; r < 4; r++) {
                int ml = wave_m * 64 + mi * 16 + (lane >> 4) * 4 + r;
                int s = m0 + ml;
                if (s < count) {
                    int n = n0 + wave_n * 64 + ni * 16 + (lane & 15);
                    atomicAdd(final_out + (size_t)tids[ml] * HID + n, acc[mi][ni][r]);
                }
            }
}

extern "C" void kernel_launch(void* const* d_in, const int* in_sizes, int n_in,
                              void* d_out, int out_size, void* d_ws, size_t ws_size,
                              hipStream_t stream) {
    const float* X  = (const float*)d_in[0];
    const float* G  = (const float*)d_in[1];
    const float* w1 = (const float*)d_in[2];
    const float* w2 = (const float*)d_in[3];
    const float* w3 = (const float*)d_in[4];

    float* out = (float*)d_out;
    float* out_final  = out;
    float* out_logits = out + (size_t)NT * HID;
    float* out_sel    = out_logits + (size_t)NT * NE;
    float* out_loss   = out_sel + (size_t)NT * TOPK;

    char* ws = (char*)d_ws;
    int*   counts     = (int*)(ws + 0);
    int*   cursor     = (int*)(ws + 64);
    int*   offsets    = (int*)(ws + 128);
    float* importance = (float*)(ws + 192);
    int*   sel_e   = (int*)(ws + 512);
    float* sel_w   = (float*)(ws + 197120);
    int*   tok_ids = (int*)(ws + 393728);
    float* slot_w  = (float*)(ws + 590336);
    unsigned short* wb1 = (unsigned short*)(ws + 786944);
    unsigned short* wb3 = (unsigned short*)(ws + 7078400);
    unsigned short* wb2 = (unsigned short*)(ws + 13369856);
    unsigned short* H   = (unsigned short*)(ws + 19661312);

    unsigned short* xb = (unsigned short*)d_out;   // dead `final` region until ffn2

    hipMemsetAsync(ws, 0, 256, stream);
    cvt_weights<<<dim3(1024, 3), 256, 0, stream>>>(w1, w3, w2, wb1, wb3, wb2);
    router_kernel<<<NT / 4, 256, 0, stream>>>(X, G, out_logits, out_sel, xb, sel_e, sel_w);
    hist_kernel<<<NT / 256, 256, 0, stream>>>(sel_e, sel_w, counts, importance);
    scan_loss<<<1, 64, 0, stream>>>(counts, cursor, offsets, importance, out_loss);
    place_kernel<<<NT / 256, 256, 0, stream>>>(sel_e, sel_w, cursor, tok_ids, slot_w);
    ffn1_kernel<<<dim3(128, 4, NE), 256, 0, stream>>>(xb, wb1, wb3, offsets, tok_ids, slot_w, H);
    hipMemsetAsync(d_out, 0, (size_t)NT * HID * sizeof(float), stream);
    ffn2_kernel<<<dim3(128, 8, NE), 256, 0, stream>>>(H, wb2, offsets, tok_ids, out_final);
}

// Round 3
// 390.516 us; speedup vs baseline: 3.0474x; 1.1559x over previous
//
#include <hip/hip_runtime.h>
#include <hip/hip_bf16.h>

#define NT 16384
#define HID 1024
#define FFN_ 256
#define NE 12
#define TOPK 3

typedef float  float4x  __attribute__((ext_vector_type(4)));
typedef short  short8x  __attribute__((ext_vector_type(8)));

__device__ __forceinline__ unsigned short f2bf(float f) {
    unsigned u = __float_as_uint(f);
    u += 0x7fffu + ((u >> 16) & 1u);
    return (unsigned short)(u >> 16);
}
__device__ __forceinline__ float bf2f(unsigned short u) {
    return __uint_as_float(((unsigned)u) << 16);
}

__device__ __forceinline__ void gl2lds16(const void* g, void* l) {
    __builtin_amdgcn_global_load_lds(
        (const __attribute__((address_space(1))) unsigned int*)g,
        (__attribute__((address_space(3))) unsigned int*)l, 16, 0, 0);
}

// ---------------- merged weight-convert + router ----------------
// blocks [0,768): fp32->bf16 weight convert (grid-stride). blocks [768,...):
// router: logits, top3, per-token weights, x->bf16. No global atomics.
__global__ __launch_bounds__(256) void router_cvt_kernel(
    const float* __restrict__ X, const float* __restrict__ G,
    const float* __restrict__ w1, const float* __restrict__ w3, const float* __restrict__ w2,
    unsigned short* __restrict__ o1, unsigned short* __restrict__ o3, unsigned short* __restrict__ o2,
    float* __restrict__ out_logits, float* __restrict__ out_sel,
    unsigned short* __restrict__ xb,
    int* __restrict__ sel_e, float* __restrict__ sel_w)
{
    __shared__ __align__(16) float gls[NE * HID];   // 48 KB (router blocks only)

    if (blockIdx.x < 768) {
        const float* s; unsigned short* d;
        int m = blockIdx.x >> 8;
        if (m == 0)      { s = w1; d = o1; }
        else if (m == 1) { s = w3; d = o3; }
        else             { s = w2; d = o2; }
        const int n4 = NE * FFN_ * HID / 4;   // 786432
        for (int i = (blockIdx.x & 255) * 256 + threadIdx.x; i < n4; i += 65536) {
            float4 v = ((const float4*)s)[i];
            ushort4 o;
            o.x = f2bf(v.x); o.y = f2bf(v.y); o.z = f2bf(v.z); o.w = f2bf(v.w);
            ((ushort4*)d)[i] = o;
        }
        return;
    }

    const int bx = blockIdx.x - 768;
    for (int i = threadIdx.x; i < NE * HID / 4; i += 256)
        ((float4*)gls)[i] = ((const float4*)G)[i];
    __syncthreads();

    const int wave = threadIdx.x >> 6, lane = threadIdx.x & 63;
    const int t = bx * 4 + wave;

    float xr[16];
    const float* xt = X + (size_t)t * HID;
    unsigned short* xbt = xb + (size_t)t * HID;
#pragma unroll
    for (int j = 0; j < 4; j++) {
        float4 v = ((const float4*)xt)[j * 64 + lane];
        xr[j*4+0] = v.x; xr[j*4+1] = v.y; xr[j*4+2] = v.z; xr[j*4+3] = v.w;
        ushort4 o;
        o.x = f2bf(v.x); o.y = f2bf(v.y); o.z = f2bf(v.z); o.w = f2bf(v.w);
        ((ushort4*)xbt)[j * 64 + lane] = o;
    }

    float logit[NE];
#pragma unroll
    for (int e = 0; e < NE; e++) {
        float s = 0.f;
#pragma unroll
        for (int j = 0; j < 4; j++) {
            float4 g = ((const float4*)gls)[e * 256 + j * 64 + lane];
            s += xr[j*4+0]*g.x + xr[j*4+1]*g.y + xr[j*4+2]*g.z + xr[j*4+3]*g.w;
        }
#pragma unroll
        for (int d = 32; d; d >>= 1) s += __shfl_xor(s, d, 64);
        logit[e] = s;
    }

    if (lane == 0) {
        float m = logit[0];
#pragma unroll
        for (int e = 1; e < NE; e++) m = fmaxf(m, logit[e]);
#pragma unroll
        for (int e = 0; e < NE; e++) out_logits[(size_t)t * NE + e] = logit[e];

        bool used[NE];
#pragma unroll
        for (int e = 0; e < NE; e++) used[e] = false;
        int   sel[TOPK];
        float w[TOPK];
        float wsum = 0.f;
#pragma unroll
        for (int k = 0; k < TOPK; k++) {
            int best = -1; float bv = -1e30f;
            for (int e = 0; e < NE; e++)
                if (!used[e] && logit[e] > bv) { bv = logit[e]; best = e; }
            used[best] = true;
            sel[k] = best;
            w[k] = __expf(bv - m);
            wsum += w[k];
        }
        float inv = 1.f / wsum;
#pragma unroll
        for (int k = 0; k < TOPK; k++) {
            float wk = w[k] * inv;
            out_sel[(size_t)t * TOPK + k] = (float)sel[k];
            sel_e[t * TOPK + k] = sel[k];
            sel_w[t * TOPK + k] = wk;
        }
    }
}

// ---------------- histogram: counts + importance via LDS aggregation ----------------
__global__ __launch_bounds__(256) void hist_kernel(
    const int* __restrict__ sel_e, const float* __restrict__ sel_w,
    int* __restrict__ counts, float* __restrict__ importance)
{
    __shared__ int   lcnt[NE];
    __shared__ float limp[NE];
    const int tid = threadIdx.x;
    if (tid < NE) { lcnt[tid] = 0; limp[tid] = 0.f; }
    __syncthreads();
    const int t = blockIdx.x * 256 + tid;
#pragma unroll
    for (int k = 0; k < TOPK; k++) {
        int e = sel_e[t * TOPK + k];
        atomicAdd(&lcnt[e], 1);
        atomicAdd(&limp[e], sel_w[t * TOPK + k]);
    }
    __syncthreads();
    if (tid < NE) {
        atomicAdd(&counts[tid], lcnt[tid]);
        atomicAdd(&importance[tid], limp[tid]);
    }
}

// ---------------- prefix scan + router loss ----------------
__global__ void scan_loss(const int* __restrict__ counts, int* __restrict__ cursor,
                          int* __restrict__ offsets, const float* __restrict__ importance,
                          float* __restrict__ loss_out)
{
    if (threadIdx.x == 0) {
        int acc = 0;
        for (int e = 0; e < NE; e++) { offsets[e] = acc; cursor[e] = acc; acc += counts[e]; }
        offsets[NE] = acc;
        float mean = 0.f;
        for (int e = 0; e < NE; e++) mean += importance[e];
        mean /= (float)NE;
        float var = 0.f;
        for (int e = 0; e < NE; e++) { float d = importance[e] - mean; var += d * d; }
        var /= (float)(NE - 1);   // ddof=1
        *loss_out = sqrtf(var);
    }
}

// ---------------- placement: block-aggregated cursor atomics + inverse map ----------------
__global__ __launch_bounds__(256) void place_kernel(
    const int* __restrict__ sel_e, const float* __restrict__ sel_w,
    int* __restrict__ cursor, int* __restrict__ tok_ids, float* __restrict__ slot_w,
    int* __restrict__ inv3)
{
    __shared__ int lcnt[NE];
    __shared__ int lbase[NE];
    const int tid = threadIdx.x;
    if (tid < NE) lcnt[tid] = 0;
    __syncthreads();
    const int t = blockIdx.x * 256 + tid;
    int e[TOPK], r[TOPK];
#pragma unroll
    for (int k = 0; k < TOPK; k++) {
        e[k] = sel_e[t * TOPK + k];
        r[k] = atomicAdd(&lcnt[e[k]], 1);
    }
    __syncthreads();
    if (tid < NE) lbase[tid] = atomicAdd(&cursor[tid], lcnt[tid]);
    __syncthreads();
#pragma unroll
    for (int k = 0; k < TOPK; k++) {
        int pos = lbase[e[k]] + r[k];
        tok_ids[pos] = t;
        slot_w[pos] = sel_w[t * TOPK + k];
        inv3[t * TOPK + k] = pos;
    }
}

// ---------------- FFN1: H = silu(Xg@W1^T)*(Xg@W3^T)*w -> bf16 ----------------
// tile 128 slots x 128 ffn, BK=32, 2x2 waves (64x64 each), XOR bank swizzle.
__global__ __launch_bounds__(256) void ffn1_kernel(
    const unsigned short* __restrict__ xb, const unsigned short* __restrict__ wb1,
    const unsigned short* __restrict__ wb3, const int* __restrict__ offsets,
    const int* __restrict__ tok_ids, const float* __restrict__ slot_w,
    unsigned short* __restrict__ H)
{
    const int e = blockIdx.z;
    const int base = offsets[e];
    const int count = offsets[e + 1] - base;
    const int m0 = blockIdx.x * 128;
    if (m0 >= count) return;
    const int n0 = blockIdx.y * 128;

    __shared__ __align__(16) unsigned short As[128 * 32];
    __shared__ __align__(16) unsigned short B1s[128 * 32];
    __shared__ __align__(16) unsigned short B3s[128 * 32];
    __shared__ int   tids[128];
    __shared__ float wts[128];

    const int tid = threadIdx.x;
    if (tid < 128) {
        int s = m0 + tid;
        tids[tid] = (s < count) ? tok_ids[base + s] : 0;
        wts[tid]  = (s < count) ? slot_w[base + s] : 0.f;
    }
    __syncthreads();

    const int wave = tid >> 6, lane = tid & 63;
    const int wave_m = wave & 1, wave_n = wave >> 1;

    // staging geometry: lane L -> tile row wave*32+(L>>2) (and +16), chunk slot L&3,
    // fetching global chunk (L&3) ^ ((row>>1)&3)   [XOR bank swizzle]
    const int srow = wave * 32 + (lane >> 2);
    const int schunk = (((lane & 3) ^ ((srow >> 1) & 3)) << 3);
    const int tokA0 = tids[srow];
    const int tokA1 = tids[srow + 16];

    const unsigned short* asrc0 = xb + (size_t)tokA0 * HID + schunk;
    const unsigned short* asrc1 = xb + (size_t)tokA1 * HID + schunk;
    const unsigned short* b1p0 = wb1 + (size_t)(e * FFN_ + n0 + srow) * HID + schunk;
    const unsigned short* b1p1 = b1p0 + 16 * HID;
    const unsigned short* b3p0 = wb3 + (size_t)(e * FFN_ + n0 + srow) * HID + schunk;
    const unsigned short* b3p1 = b3p0 + 16 * HID;

    char* aD0  = (char*)As  + wave * 2048;  char* aD1  = aD0 + 1024;
    char* b1D0 = (char*)B1s + wave * 2048;  char* b1D1 = b1D0 + 1024;
    char* b3D0 = (char*)B3s + wave * 2048;  char* b3D1 = b3D0 + 1024;

    const int r15 = lane & 15;
    const int rchunk = (((lane >> 4) ^ ((r15 >> 1) & 3)) << 3);   // reader slot (elements)

    float4x acc1[4][4], acc3[4][4];
#pragma unroll
    for (int mi = 0; mi < 4; mi++)
#pragma unroll
        for (int ni = 0; ni < 4; ni++) {
            acc1[mi][ni] = (float4x){0.f, 0.f, 0.f, 0.f};
            acc3[mi][ni] = (float4x){0.f, 0.f, 0.f, 0.f};
        }

    for (int kk = 0; kk < HID / 32; kk++) {
        __syncthreads();
        gl2lds16(asrc0, aD0);  gl2lds16(asrc1, aD1);
        gl2lds16(b1p0, b1D0);  gl2lds16(b1p1, b1D1);
        gl2lds16(b3p0, b3D0);  gl2lds16(b3p1, b3D1);
        __syncthreads();
        asrc0 += 32; asrc1 += 32; b1p0 += 32; b1p1 += 32; b3p0 += 32; b3p1 += 32;

        short8x a[4], b1f[4], b3f[4];
#pragma unroll
        for (int mi = 0; mi < 4; mi++)
            a[mi] = *(const short8x*)(As + (wave_m * 64 + mi * 16 + r15) * 32 + rchunk);
#pragma unroll
        for (int ni = 0; ni < 4; ni++) {
            b1f[ni] = *(const short8x*)(B1s + (wave_n * 64 + ni * 16 + r15) * 32 + rchunk);
            b3f[ni] = *(const short8x*)(B3s + (wave_n * 64 + ni * 16 + r15) * 32 + rchunk);
        }
#pragma unroll
        for (int mi = 0; mi < 4; mi++)
#pragma unroll
            for (int ni = 0; ni < 4; ni++) {
                acc1[mi][ni] = __builtin_amdgcn_mfma_f32_16x16x32_bf16(a[mi], b1f[ni], acc1[mi][ni], 0, 0, 0);
                acc3[mi][ni] = __builtin_amdgcn_mfma_f32_16x16x32_bf16(a[mi], b3f[ni], acc3[mi][ni], 0, 0, 0);
            }
    }

    const int laneh = lane >> 4;
#pragma unroll
    for (int mi = 0; mi < 4; mi++)
#pragma unroll
        for (int ni = 0; ni < 4; ni++)
#pragma unroll
            for (int r = 0; r < 4; r++) {
                int ml = wave_m * 64 + mi * 16 + laneh * 4 + r;
                int s = m0 + ml;
                if (s < count) {
                    float v1 = acc1[mi][ni][r];
                    float v3 = acc3[mi][ni][r];
                    float h = v1 * (1.f / (1.f + __expf(-v1))) * v3 * wts[ml];
                    int n = n0 + wave_n * 64 + ni * 16 + r15;
                    H[(size_t)(base + s) * FFN_ + n] = f2bf(h);
                }
            }
}

// ---------------- FFN2 (store variant): Obuf[slot][nc] = H @ W2^T slice, bf16 ----------
// tile 128 slots x 128 hid, K=256, BK=32, 2x2 waves, XOR swizzle, plain stores.
__global__ __launch_bounds__(256) void ffn2_store(
    const unsigned short* __restrict__ H, const unsigned short* __restrict__ wb2,
    const int* __restrict__ offsets, unsigned short* __restrict__ Obuf,
    int co, int nc)
{
    const int e = blockIdx.z;
    const int base = offsets[e];
    const int count = offsets[e + 1] - base;
    const int m0 = blockIdx.x * 128;
    if (m0 >= count) return;
    const int n0g = co + blockIdx.y * 128;   // global hid col

    __shared__ __align__(16) unsigned short As[128 * 32];
    __shared__ __align__(16) unsigned short Bs[128 * 32];

    const int tid = threadIdx.x;
    const int wave = tid >> 6, lane = tid & 63;
    const int wave_m = wave & 1, wave_n = wave >> 1;

    const int srow = wave * 32 + (lane >> 2);
    const int schunk = (((lane & 3) ^ ((srow >> 1) & 3)) << 3);

    const unsigned short* a0 = H + (size_t)(base + m0 + srow) * FFN_ + schunk;
    const unsigned short* a1 = a0 + 16 * FFN_;
    const unsigned short* b0 = wb2 + (size_t)(e * HID + n0g + srow) * FFN_ + schunk;
    const unsigned short* b1 = b0 + 16 * FFN_;

    char* aD0 = (char*)As + wave * 2048;  char* aD1 = aD0 + 1024;
    char* bD0 = (char*)Bs + wave * 2048;  char* bD1 = bD0 + 1024;

    const int r15 = lane & 15;
    const int rchunk = (((lane >> 4) ^ ((r15 >> 1) & 3)) << 3);

    float4x acc[4][4];
#pragma unroll
    for (int mi = 0; mi < 4; mi++)
#pragma unroll
        for (int ni = 0; ni < 4; ni++) acc[mi][ni] = (float4x){0.f, 0.f, 0.f, 0.f};

    for (int kk = 0; kk < FFN_ / 32; kk++) {
        __syncthreads();
        gl2lds16(a0, aD0);  gl2lds16(a1, aD1);
        gl2lds16(b0, bD0);  gl2lds16(b1, bD1);
        __syncthreads();
        a0 += 32; a1 += 32; b0 += 32; b1 += 32;

        short8x af[4], bf[4];
#pragma unroll
        for (int mi = 0; mi < 4; mi++)
            af[mi] = *(const short8x*)(As + (wave_m * 64 + mi * 16 + r15) * 32 + rchunk);
#pragma unroll
        for (int ni = 0; ni < 4; ni++)
            bf[ni] = *(const short8x*)(Bs + (wave_n * 64 + ni * 16 + r15) * 32 + rchunk);
#pragma unroll
        for (int mi = 0; mi < 4; mi++)
#pragma unroll
            for (int ni = 0; ni < 4; ni++)
                acc[mi][ni] = __builtin_amdgcn_mfma_f32_16x16x32_bf16(af[mi], bf[ni], acc[mi][ni], 0, 0, 0);
    }

    const int laneh = lane >> 4;
#pragma unroll
    for (int mi = 0; mi < 4; mi++)
#pragma unroll
        for (int ni = 0; ni < 4; ni++)
#pragma unroll
            for (int r = 0; r < 4; r++) {
                int ml = wave_m * 64 + mi * 16 + laneh * 4 + r;
                int s = m0 + ml;
                if (s < count) {
                    int col = (n0g - co) + wave_n * 64 + ni * 16 + r15;
                    Obuf[(size_t)(base + s) * nc + col] = f2bf(acc[mi][ni][r]);
                }
            }
}

// ---------------- combine: final[t][co..] = sum over token's 3 slots ----------------
__global__ __launch_bounds__(256) void combine_kernel(
    const unsigned short* __restrict__ Obuf, const int* __restrict__ inv3,
    float* __restrict__ final_out, int co, int pt_shift)
{
    const int idx = blockIdx.x * 256 + threadIdx.x;
    const int per_t = 1 << pt_shift;          // nc/4 ushort4 groups per token
    const int t = idx >> pt_shift;
    const int c4 = idx & (per_t - 1);
    const int s0 = inv3[t * TOPK + 0];
    const int s1 = inv3[t * TOPK + 1];
    const int s2 = inv3[t * TOPK + 2];
    const ushort4* O = (const ushort4*)Obuf;
    ushort4 u0 = O[(size_t)s0 * per_t + c4];
    ushort4 u1 = O[(size_t)s1 * per_t + c4];
    ushort4 u2 = O[(size_t)s2 * per_t + c4];
    float4 r;
    r.x = bf2f(u0.x) + bf2f(u1.x) + bf2f(u2.x);
    r.y = bf2f(u0.y) + bf2f(u1.y) + bf2f(u2.y);
    r.z = bf2f(u0.z) + bf2f(u1.z) + bf2f(u2.z);
    r.w = bf2f(u0.w) + bf2f(u1.w) + bf2f(u2.w);
    ((float4*)(final_out + (size_t)t * HID + co))[c4] = r;
}

// ---------------- FFN2 fallback (atomic scatter) — only if ws too small -------------
__global__ __launch_bounds__(256) void ffn2_atomic(
    const unsigned short* __restrict__ H, const unsigned short* __restrict__ wb2,
    const int* __restrict__ offsets, const int* __restrict__ tok_ids,
    float* __restrict__ final_out)
{
    const int e = blockIdx.z;
    const int base = offsets[e];
    const int count = offsets[e + 1] - base;
    const int m0 = blockIdx.x * 128;
    if (m0 >= count) return;
    const int n0 = blockIdx.y * 128;

    __shared__ __align__(16) unsigned short As[128 * 32];
    __shared__ __align__(16) unsigned short Bs[128 * 32];
    __shared__ int tids[128];

    const int tid = threadIdx.x;
    if (tid < 128) {
        int s = m0 + tid;
        tids[tid] = (s < count) ? tok_ids[base + s] : 0;
    }
    __syncthreads();

    const int wave = tid >> 6, lane = tid & 63;
    const int wave_m = wave & 1, wave_n = wave >> 1;

    const int srow = wave * 32 + (lane >> 2);
    const int schunk = (((lane & 3) ^ ((srow >> 1) & 3)) << 3);
    const unsigned short* a0 = H + (size_t)(base + m0 + srow) * FFN_ + schunk;
    const unsigned short* a1 = a0 + 16 * FFN_;
    const unsigned short* b0 = wb2 + (size_t)(e * HID + n0 + srow) * FFN_ + schunk;
    const unsigned short* b1 = b0 + 16 * FFN_;

    char* aD0 = (char*)As + wave * 2048;  char* aD1 = aD0 + 1024;
    char* bD0 = (char*)Bs + wave * 2048;  char* bD1 = bD0 + 1024;

    const int r15 = lane & 15;
    const int rchunk = (((lane >> 4) ^ ((r15 >> 1) & 3)) << 3);

    float4x acc[4][4];
#pragma unroll
    for (int mi = 0; mi < 4; mi++)
#pragma unroll
        for (int ni = 0; ni < 4; ni++) acc[mi][ni] = (float4x){0.f, 0.f, 0.f, 0.f};

    for (int kk = 0; kk < FFN_ / 32; kk++) {
        __syncthreads();
        gl2lds16(a0, aD0);  gl2lds16(a1, aD1);
        gl2lds16(b0, bD0);  gl2lds16(b1, bD1);
        __syncthreads();
        a0 += 32; a1 += 32; b0 += 32; b1 += 32;

        short8x af[4], bf[4];
#pragma unroll
        for (int mi = 0; mi < 4; mi++)
            af[mi] = *(const short8x*)(As + (wave_m * 64 + mi * 16 + r15) * 32 + rchunk);
#pragma unroll
        for (int ni = 0; ni < 4; ni++)
            bf[ni] = *(const short8x*)(Bs + (wave_n * 64 + ni * 16 + r15) * 32 + rchunk);
#pragma unroll
        for (int mi = 0; mi < 4; mi++)
#pragma unroll
            for (int ni = 0; ni < 4; ni++)
                acc[mi][ni] = __builtin_amdgcn_mfma_f32_16x16x32_bf16(af[mi], bf[ni], acc[mi][ni], 0, 0, 0);
    }

    const int laneh = lane >> 4;
#pragma unroll
    for (int mi = 0; mi < 4; mi++)
#pragma unroll
        for (int ni = 0; ni < 4; ni++)
#pragma unroll
            for (int r = 0; r < 4; r++) {
                int ml = wave_m * 64 + mi * 16 + laneh * 4 + r;
                int s = m0 + ml;
                if (s < count) {
                    int n = n0 + wave_n * 64 + ni * 16 + r15;
                    atomicAdd(final_out + (size_t)tids[ml] * HID + n, acc[mi][ni][r]);
                }
            }
}

extern "C" void kernel_launch(void* const* d_in, const int* in_sizes, int n_in,
                              void* d_out, int out_size, void* d_ws, size_t ws_size,
                              hipStream_t stream) {
    const float* X  = (const float*)d_in[0];
    const float* G  = (const float*)d_in[1];
    const float* w1 = (const float*)d_in[2];
    const float* w2 = (const float*)d_in[3];
    const float* w3 = (const float*)d_in[4];

    float* out = (float*)d_out;
    float* out_final  = out;
    float* out_logits = out + (size_t)NT * HID;
    float* out_sel    = out_logits + (size_t)NT * NE;
    float* out_loss   = out_sel + (size_t)NT * TOPK;

    char* ws = (char*)d_ws;
    int*   counts     = (int*)(ws + 0);
    int*   cursor     = (int*)(ws + 64);
    int*   offsets    = (int*)(ws + 128);
    float* importance = (float*)(ws + 192);
    int*   sel_e   = (int*)(ws + 512);
    float* sel_w   = (float*)(ws + 197120);
    int*   tok_ids = (int*)(ws + 393728);
    float* slot_w  = (float*)(ws + 590336);
    unsigned short* wb1 = (unsigned short*)(ws + 786944);
    unsigned short* wb3 = (unsigned short*)(ws + 7078400);
    unsigned short* wb2 = (unsigned short*)(ws + 13369856);
    unsigned short* H   = (unsigned short*)(ws + 19661312);   // 49280 x 256 bf16
    int*  inv3          = (int*)(ws + 44892672);              // NT*3 ints
    const size_t obase  = 45089280;
    unsigned short* Obuf = (unsigned short*)(ws + obase);

    unsigned short* xb = (unsigned short*)d_out;   // dead `final` region until ffn2

    // pick Obuf column-pass width by available scratch
    int nc = 0;
    if      (ws_size >= obase + (size_t)NT * TOPK * 1024 * 2) nc = 1024;
    else if (ws_size >= obase + (size_t)NT * TOPK * 512  * 2) nc = 512;
    else if (ws_size >= obase + (size_t)NT * TOPK * 256  * 2) nc = 256;

    hipMemsetAsync(ws, 0, 256, stream);
    router_cvt_kernel<<<768 + NT / 4, 256, 0, stream>>>(
        X, G, w1, w3, w2, wb1, wb3, wb2, out_logits, out_sel, xb, sel_e, sel_w);
    hist_kernel<<<NT / 256, 256, 0, stream>>>(sel_e, sel_w, counts, importance);
    scan_loss<<<1, 64, 0, stream>>>(counts, cursor, offsets, importance, out_loss);
    place_kernel<<<NT / 256, 256, 0, stream>>>(sel_e, sel_w, cursor, tok_ids, slot_w, inv3);
    ffn1_kernel<<<dim3(48, 2, NE), 256, 0, stream>>>(xb, wb1, wb3, offsets, tok_ids, slot_w, H);

    if (nc) {
        const int np = 1024 / nc;
        const int pt_shift = (nc == 1024) ? 8 : (nc == 512 ? 7 : 6);
        for (int p = 0; p < np; p++) {
            ffn2_store<<<dim3(48, nc / 128, NE), 256, 0, stream>>>(
                H, wb2, offsets, Obuf, p * nc, nc);
            combine_kernel<<<(NT << pt_shift) / 256, 256, 0, stream>>>(
                Obuf, inv3, out_final, p * nc, pt_shift);
        }
    } else {
        hipMemsetAsync(d_out, 0, (size_t)NT * HID * sizeof(float), stream);
        ffn2_atomic<<<dim3(48, 8, NE), 256, 0, stream>>>(H, wb2, offsets, tok_ids, out_final);
    }
}

// Round 4
// 374.295 us; speedup vs baseline: 3.1795x; 1.0433x over previous
//
#include <hip/hip_runtime.h>
#include <hip/hip_bf16.h>

#define NT 16384
#define HID 1024
#define FFN_ 256
#define NE 12
#define TOPK 3

typedef float  float4x  __attribute__((ext_vector_type(4)));
typedef short  short8x  __attribute__((ext_vector_type(8)));

__device__ __forceinline__ unsigned short f2bf(float f) {
    unsigned u = __float_as_uint(f);
    u += 0x7fffu + ((u >> 16) & 1u);
    return (unsigned short)(u >> 16);
}
__device__ __forceinline__ float bf2f(unsigned short u) {
    return __uint_as_float(((unsigned)u) << 16);
}

__device__ __forceinline__ void gl2lds16(const void* g, void* l) {
    __builtin_amdgcn_global_load_lds(
        (const __attribute__((address_space(1))) unsigned int*)g,
        (__attribute__((address_space(3))) unsigned int*)l, 16, 0, 0);
}

// ---------------- merged weight-convert + router ----------------
__global__ __launch_bounds__(256) void router_cvt_kernel(
    const float* __restrict__ X, const float* __restrict__ G,
    const float* __restrict__ w1, const float* __restrict__ w3, const float* __restrict__ w2,
    unsigned short* __restrict__ o1, unsigned short* __restrict__ o3, unsigned short* __restrict__ o2,
    float* __restrict__ out_logits, float* __restrict__ out_sel,
    unsigned short* __restrict__ xb,
    int* __restrict__ sel_e, float* __restrict__ sel_w)
{
    __shared__ __align__(16) float gls[NE * HID];   // 48 KB (router blocks only)

    if (blockIdx.x < 768) {
        const float* s; unsigned short* d;
        int m = blockIdx.x >> 8;
        if (m == 0)      { s = w1; d = o1; }
        else if (m == 1) { s = w3; d = o3; }
        else             { s = w2; d = o2; }
        const int n4 = NE * FFN_ * HID / 4;   // 786432
        for (int i = (blockIdx.x & 255) * 256 + threadIdx.x; i < n4; i += 65536) {
            float4 v = ((const float4*)s)[i];
            ushort4 o;
            o.x = f2bf(v.x); o.y = f2bf(v.y); o.z = f2bf(v.z); o.w = f2bf(v.w);
            ((ushort4*)d)[i] = o;
        }
        return;
    }

    const int bx = blockIdx.x - 768;
    for (int i = threadIdx.x; i < NE * HID / 4; i += 256)
        ((float4*)gls)[i] = ((const float4*)G)[i];
    __syncthreads();

    const int wave = threadIdx.x >> 6, lane = threadIdx.x & 63;
    const int t = bx * 4 + wave;

    float xr[16];
    const float* xt = X + (size_t)t * HID;
    unsigned short* xbt = xb + (size_t)t * HID;
#pragma unroll
    for (int j = 0; j < 4; j++) {
        float4 v = ((const float4*)xt)[j * 64 + lane];
        xr[j*4+0] = v.x; xr[j*4+1] = v.y; xr[j*4+2] = v.z; xr[j*4+3] = v.w;
        ushort4 o;
        o.x = f2bf(v.x); o.y = f2bf(v.y); o.z = f2bf(v.z); o.w = f2bf(v.w);
        ((ushort4*)xbt)[j * 64 + lane] = o;
    }

    float logit[NE];
#pragma unroll
    for (int e = 0; e < NE; e++) {
        float s = 0.f;
#pragma unroll
        for (int j = 0; j < 4; j++) {
            float4 g = ((const float4*)gls)[e * 256 + j * 64 + lane];
            s += xr[j*4+0]*g.x + xr[j*4+1]*g.y + xr[j*4+2]*g.z + xr[j*4+3]*g.w;
        }
#pragma unroll
        for (int d = 32; d; d >>= 1) s += __shfl_xor(s, d, 64);
        logit[e] = s;
    }

    if (lane == 0) {
        float m = logit[0];
#pragma unroll
        for (int e = 1; e < NE; e++) m = fmaxf(m, logit[e]);
#pragma unroll
        for (int e = 0; e < NE; e++) out_logits[(size_t)t * NE + e] = logit[e];

        bool used[NE];
#pragma unroll
        for (int e = 0; e < NE; e++) used[e] = false;
        int   sel[TOPK];
        float w[TOPK];
        float wsum = 0.f;
#pragma unroll
        for (int k = 0; k < TOPK; k++) {
            int best = -1; float bv = -1e30f;
            for (int e = 0; e < NE; e++)
                if (!used[e] && logit[e] > bv) { bv = logit[e]; best = e; }
            used[best] = true;
            sel[k] = best;
            w[k] = __expf(bv - m);
            wsum += w[k];
        }
        float inv = 1.f / wsum;
#pragma unroll
        for (int k = 0; k < TOPK; k++) {
            float wk = w[k] * inv;
            out_sel[(size_t)t * TOPK + k] = (float)sel[k];
            sel_e[t * TOPK + k] = sel[k];
            sel_w[t * TOPK + k] = wk;
        }
    }
}

// ---------------- histogram: counts + importance via LDS aggregation ----------------
__global__ __launch_bounds__(256) void hist_kernel(
    const int* __restrict__ sel_e, const float* __restrict__ sel_w,
    int* __restrict__ counts, float* __restrict__ importance)
{
    __shared__ int   lcnt[NE];
    __shared__ float limp[NE];
    const int tid = threadIdx.x;
    if (tid < NE) { lcnt[tid] = 0; limp[tid] = 0.f; }
    __syncthreads();
    const int t = blockIdx.x * 256 + tid;
#pragma unroll
    for (int k = 0; k < TOPK; k++) {
        int e = sel_e[t * TOPK + k];
        atomicAdd(&lcnt[e], 1);
        atomicAdd(&limp[e], sel_w[t * TOPK + k]);
    }
    __syncthreads();
    if (tid < NE) {
        atomicAdd(&counts[tid], lcnt[tid]);
        atomicAdd(&importance[tid], limp[tid]);
    }
}

// ---------------- prefix scan + tile map + router loss ----------------
__global__ void scan_loss(const int* __restrict__ counts, int* __restrict__ cursor,
                          int* __restrict__ offsets, int* __restrict__ tile_base,
                          const float* __restrict__ importance,
                          float* __restrict__ loss_out)
{
    if (threadIdx.x == 0) {
        int acc = 0, tb = 0;
        for (int e = 0; e < NE; e++) {
            offsets[e] = acc; cursor[e] = acc; tile_base[e] = tb;
            tb += (counts[e] + 127) >> 7;
            acc += counts[e];
        }
        offsets[NE] = acc;
        tile_base[NE] = tb;
        float mean = 0.f;
        for (int e = 0; e < NE; e++) mean += importance[e];
        mean /= (float)NE;
        float var = 0.f;
        for (int e = 0; e < NE; e++) { float d = importance[e] - mean; var += d * d; }
        var /= (float)(NE - 1);   // ddof=1
        *loss_out = sqrtf(var);
    }
}

// ---------------- placement: block-aggregated cursor atomics + inverse map ----------------
__global__ __launch_bounds__(256) void place_kernel(
    const int* __restrict__ sel_e, const float* __restrict__ sel_w,
    int* __restrict__ cursor, int* __restrict__ tok_ids, float* __restrict__ slot_w,
    int* __restrict__ inv3)
{
    __shared__ int lcnt[NE];
    __shared__ int lbase[NE];
    const int tid = threadIdx.x;
    if (tid < NE) lcnt[tid] = 0;
    __syncthreads();
    const int t = blockIdx.x * 256 + tid;
    int e[TOPK], r[TOPK];
#pragma unroll
    for (int k = 0; k < TOPK; k++) {
        e[k] = sel_e[t * TOPK + k];
        r[k] = atomicAdd(&lcnt[e[k]], 1);
    }
    __syncthreads();
    if (tid < NE) lbase[tid] = atomicAdd(&cursor[tid], lcnt[tid]);
    __syncthreads();
#pragma unroll
    for (int k = 0; k < TOPK; k++) {
        int pos = lbase[e[k]] + r[k];
        tok_ids[pos] = t;
        slot_w[pos] = sel_w[t * TOPK + k];
        inv3[t * TOPK + k] = pos;
    }
}

// ---------------- FFN1: H = silu(Xg@W1^T)*(Xg@W3^T)*w -> bf16 ----------------
// 128 slots x 128 ffn, BK=32, 2x2 waves, XOR swizzle, 2-stage pipelined LDS,
// flattened (expert, m-tile) grid via tile_base.
__global__ __launch_bounds__(256) void ffn1_kernel(
    const unsigned short* __restrict__ xb, const unsigned short* __restrict__ wb1,
    const unsigned short* __restrict__ wb3, const int* __restrict__ offsets,
    const int* __restrict__ tile_base,
    const int* __restrict__ tok_ids, const float* __restrict__ slot_w,
    unsigned short* __restrict__ H)
{
    const int bx = blockIdx.x;
    if (bx >= tile_base[NE]) return;
    int e = 0;
    while (bx >= tile_base[e + 1]) e++;
    const int base = offsets[e];
    const int count = offsets[e + 1] - base;
    const int m0 = (bx - tile_base[e]) << 7;
    const int n0 = blockIdx.y * 128;

    __shared__ __align__(16) unsigned short As[2][4096];
    __shared__ __align__(16) unsigned short B1s[2][4096];
    __shared__ __align__(16) unsigned short B3s[2][4096];
    __shared__ int   tids[128];
    __shared__ float wts[128];

    const int tid = threadIdx.x;
    if (tid < 128) {
        int s = m0 + tid;
        tids[tid] = (s < count) ? tok_ids[base + s] : 0;
        wts[tid]  = (s < count) ? slot_w[base + s] : 0.f;
    }
    __syncthreads();

    const int wave = tid >> 6, lane = tid & 63;
    const int wave_m = wave & 1, wave_n = wave >> 1;

    const int srow = wave * 32 + (lane >> 2);
    const int schunk = (((lane & 3) ^ ((srow >> 1) & 3)) << 3);
    const int tokA0 = tids[srow];
    const int tokA1 = tids[srow + 16];

    const unsigned short* asrc0 = xb + (size_t)tokA0 * HID + schunk;
    const unsigned short* asrc1 = xb + (size_t)tokA1 * HID + schunk;
    const unsigned short* b1p0 = wb1 + (size_t)(e * FFN_ + n0 + srow) * HID + schunk;
    const unsigned short* b1p1 = b1p0 + 16 * HID;
    const unsigned short* b3p0 = wb3 + (size_t)(e * FFN_ + n0 + srow) * HID + schunk;
    const unsigned short* b3p1 = b3p0 + 16 * HID;

    const int woff = wave * 2048;   // byte offset within a buffer

#define FFN1_STAGE(p) do {                                             \
        char* aD  = (char*)&As[p][0]  + woff;                          \
        char* b1D = (char*)&B1s[p][0] + woff;                          \
        char* b3D = (char*)&B3s[p][0] + woff;                          \
        gl2lds16(asrc0, aD);  gl2lds16(asrc1, aD + 1024);              \
        gl2lds16(b1p0, b1D);  gl2lds16(b1p1, b1D + 1024);              \
        gl2lds16(b3p0, b3D);  gl2lds16(b3p1, b3D + 1024);              \
        asrc0 += 32; asrc1 += 32; b1p0 += 32; b1p1 += 32;              \
        b3p0 += 32; b3p1 += 32; } while (0)

    const int r15 = lane & 15;
    const int rchunk = (((lane >> 4) ^ ((r15 >> 1) & 3)) << 3);

    float4x acc1[4][4], acc3[4][4];
#pragma unroll
    for (int mi = 0; mi < 4; mi++)
#pragma unroll
        for (int ni = 0; ni < 4; ni++) {
            acc1[mi][ni] = (float4x){0.f, 0.f, 0.f, 0.f};
            acc3[mi][ni] = (float4x){0.f, 0.f, 0.f, 0.f};
        }

    FFN1_STAGE(0);
    for (int kk = 0; kk < HID / 32; kk++) {
        __syncthreads();                 // drains buf[kk&1] DMAs (in flight since kk-1)
        if (kk + 1 < HID / 32) FFN1_STAGE((kk + 1) & 1);   // overlaps with compute
        const int p = kk & 1;

        short8x a[4], b1f[4], b3f[4];
#pragma unroll
        for (int mi = 0; mi < 4; mi++)
            a[mi] = *(const short8x*)(&As[p][0] + (wave_m * 64 + mi * 16 + r15) * 32 + rchunk);
#pragma unroll
        for (int ni = 0; ni < 4; ni++) {
            b1f[ni] = *(const short8x*)(&B1s[p][0] + (wave_n * 64 + ni * 16 + r15) * 32 + rchunk);
            b3f[ni] = *(const short8x*)(&B3s[p][0] + (wave_n * 64 + ni * 16 + r15) * 32 + rchunk);
        }
#pragma unroll
        for (int mi = 0; mi < 4; mi++)
#pragma unroll
            for (int ni = 0; ni < 4; ni++) {
                acc1[mi][ni] = __builtin_amdgcn_mfma_f32_16x16x32_bf16(a[mi], b1f[ni], acc1[mi][ni], 0, 0, 0);
                acc3[mi][ni] = __builtin_amdgcn_mfma_f32_16x16x32_bf16(a[mi], b3f[ni], acc3[mi][ni], 0, 0, 0);
            }
    }
#undef FFN1_STAGE

    const int laneh = lane >> 4;
#pragma unroll
    for (int mi = 0; mi < 4; mi++)
#pragma unroll
        for (int ni = 0; ni < 4; ni++)
#pragma unroll
            for (int r = 0; r < 4; r++) {
                int ml = wave_m * 64 + mi * 16 + laneh * 4 + r;
                int s = m0 + ml;
                if (s < count) {
                    float v1 = acc1[mi][ni][r];
                    float v3 = acc3[mi][ni][r];
                    float h = v1 * (1.f / (1.f + __expf(-v1))) * v3 * wts[ml];
                    int n = n0 + wave_n * 64 + ni * 16 + r15;
                    H[(size_t)(base + s) * FFN_ + n] = f2bf(h);
                }
            }
}

// ---------------- FFN2 (store): Obuf[slot][nc] = H @ W2^T slice, bf16 ----------
// 128 slots x 128 hid, K=256, BK=32, pipelined, flattened grid.
__global__ __launch_bounds__(256) void ffn2_store(
    const unsigned short* __restrict__ H, const unsigned short* __restrict__ wb2,
    const int* __restrict__ offsets, const int* __restrict__ tile_base,
    unsigned short* __restrict__ Obuf, int co, int nc)
{
    const int bx = blockIdx.x;
    if (bx >= tile_base[NE]) return;
    int e = 0;
    while (bx >= tile_base[e + 1]) e++;
    const int base = offsets[e];
    const int count = offsets[e + 1] - base;
    const int m0 = (bx - tile_base[e]) << 7;
    const int n0g = co + blockIdx.y * 128;

    __shared__ __align__(16) unsigned short As[2][4096];
    __shared__ __align__(16) unsigned short Bs[2][4096];

    const int tid = threadIdx.x;
    const int wave = tid >> 6, lane = tid & 63;
    const int wave_m = wave & 1, wave_n = wave >> 1;

    const int srow = wave * 32 + (lane >> 2);
    const int schunk = (((lane & 3) ^ ((srow >> 1) & 3)) << 3);

    const unsigned short* a0 = H + (size_t)(base + m0 + srow) * FFN_ + schunk;
    const unsigned short* a1 = a0 + 16 * FFN_;
    const unsigned short* b0 = wb2 + (size_t)(e * HID + n0g + srow) * FFN_ + schunk;
    const unsigned short* b1 = b0 + 16 * FFN_;

    const int woff = wave * 2048;

#define FFN2_STAGE(p) do {                                             \
        char* aD = (char*)&As[p][0] + woff;                            \
        char* bD = (char*)&Bs[p][0] + woff;                            \
        gl2lds16(a0, aD);  gl2lds16(a1, aD + 1024);                    \
        gl2lds16(b0, bD);  gl2lds16(b1, bD + 1024);                    \
        a0 += 32; a1 += 32; b0 += 32; b1 += 32; } while (0)

    const int r15 = lane & 15;
    const int rchunk = (((lane >> 4) ^ ((r15 >> 1) & 3)) << 3);

    float4x acc[4][4];
#pragma unroll
    for (int mi = 0; mi < 4; mi++)
#pragma unroll
        for (int ni = 0; ni < 4; ni++) acc[mi][ni] = (float4x){0.f, 0.f, 0.f, 0.f};

    FFN2_STAGE(0);
    for (int kk = 0; kk < FFN_ / 32; kk++) {
        __syncthreads();
        if (kk + 1 < FFN_ / 32) FFN2_STAGE((kk + 1) & 1);
        const int p = kk & 1;

        short8x af[4], bf[4];
#pragma unroll
        for (int mi = 0; mi < 4; mi++)
            af[mi] = *(const short8x*)(&As[p][0] + (wave_m * 64 + mi * 16 + r15) * 32 + rchunk);
#pragma unroll
        for (int ni = 0; ni < 4; ni++)
            bf[ni] = *(const short8x*)(&Bs[p][0] + (wave_n * 64 + ni * 16 + r15) * 32 + rchunk);
#pragma unroll
        for (int mi = 0; mi < 4; mi++)
#pragma unroll
            for (int ni = 0; ni < 4; ni++)
                acc[mi][ni] = __builtin_amdgcn_mfma_f32_16x16x32_bf16(af[mi], bf[ni], acc[mi][ni], 0, 0, 0);
    }
#undef FFN2_STAGE

    const int laneh = lane >> 4;
#pragma unroll
    for (int mi = 0; mi < 4; mi++)
#pragma unroll
        for (int ni = 0; ni < 4; ni++)
#pragma unroll
            for (int r = 0; r < 4; r++) {
                int ml = wave_m * 64 + mi * 16 + laneh * 4 + r;
                int s = m0 + ml;
                if (s < count) {
                    int col = (n0g - co) + wave_n * 64 + ni * 16 + r15;
                    Obuf[(size_t)(base + s) * nc + col] = f2bf(acc[mi][ni][r]);
                }
            }
}

// ---------------- combine: final[t][co..] = sum over token's 3 slots ----------------
__global__ __launch_bounds__(256) void combine_kernel(
    const unsigned short* __restrict__ Obuf, const int* __restrict__ inv3,
    float* __restrict__ final_out, int co, int pt_shift)
{
    const int idx = blockIdx.x * 256 + threadIdx.x;
    const int per_t = 1 << pt_shift;
    const int t = idx >> pt_shift;
    const int c4 = idx & (per_t - 1);
    const int s0 = inv3[t * TOPK + 0];
    const int s1 = inv3[t * TOPK + 1];
    const int s2 = inv3[t * TOPK + 2];
    const ushort4* O = (const ushort4*)Obuf;
    ushort4 u0 = O[(size_t)s0 * per_t + c4];
    ushort4 u1 = O[(size_t)s1 * per_t + c4];
    ushort4 u2 = O[(size_t)s2 * per_t + c4];
    float4 r;
    r.x = bf2f(u0.x) + bf2f(u1.x) + bf2f(u2.x);
    r.y = bf2f(u0.y) + bf2f(u1.y) + bf2f(u2.y);
    r.z = bf2f(u0.z) + bf2f(u1.z) + bf2f(u2.z);
    r.w = bf2f(u0.w) + bf2f(u1.w) + bf2f(u2.w);
    ((float4*)(final_out + (size_t)t * HID + co))[c4] = r;
}

// ---------------- FFN2 fallback (atomic scatter) — only if ws too small -------------
__global__ __launch_bounds__(256) void ffn2_atomic(
    const unsigned short* __restrict__ H, const unsigned short* __restrict__ wb2,
    const int* __restrict__ offsets, const int* __restrict__ tile_base,
    const int* __restrict__ tok_ids, float* __restrict__ final_out)
{
    const int bx = blockIdx.x;
    if (bx >= tile_base[NE]) return;
    int e = 0;
    while (bx >= tile_base[e + 1]) e++;
    const int base = offsets[e];
    const int count = offsets[e + 1] - base;
    const int m0 = (bx - tile_base[e]) << 7;
    const int n0 = blockIdx.y * 128;

    __shared__ __align__(16) unsigned short As[2][4096];
    __shared__ __align__(16) unsigned short Bs[2][4096];
    __shared__ int tids[128];

    const int tid = threadIdx.x;
    if (tid < 128) {
        int s = m0 + tid;
        tids[tid] = (s < count) ? tok_ids[base + s] : 0;
    }
    __syncthreads();

    const int wave = tid >> 6, lane = tid & 63;
    const int wave_m = wave & 1, wave_n = wave >> 1;

    const int srow = wave * 32 + (lane >> 2);
    const int schunk = (((lane & 3) ^ ((srow >> 1) & 3)) << 3);
    const unsigned short* a0 = H + (size_t)(base + m0 + srow) * FFN_ + schunk;
    const unsigned short* a1 = a0 + 16 * FFN_;
    const unsigned short* b0 = wb2 + (size_t)(e * HID + n0 + srow) * FFN_ + schunk;
    const unsigned short* b1 = b0 + 16 * FFN_;

    const int woff = wave * 2048;
#define FFN2A_STAGE(p) do {                                            \
        char* aD = (char*)&As[p][0] + woff;                            \
        char* bD = (char*)&Bs[p][0] + woff;                            \
        gl2lds16(a0, aD);  gl2lds16(a1, aD + 1024);                    \
        gl2lds16(b0, bD);  gl2lds16(b1, bD + 1024);                    \
        a0 += 32; a1 += 32; b0 += 32; b1 += 32; } while (0)

    const int r15 = lane & 15;
    const int rchunk = (((lane >> 4) ^ ((r15 >> 1) & 3)) << 3);

    float4x acc[4][4];
#pragma unroll
    for (int mi = 0; mi < 4; mi++)
#pragma unroll
        for (int ni = 0; ni < 4; ni++) acc[mi][ni] = (float4x){0.f, 0.f, 0.f, 0.f};

    FFN2A_STAGE(0);
    for (int kk = 0; kk < FFN_ / 32; kk++) {
        __syncthreads();
        if (kk + 1 < FFN_ / 32) FFN2A_STAGE((kk + 1) & 1);
        const int p = kk & 1;
        short8x af[4], bf[4];
#pragma unroll
        for (int mi = 0; mi < 4; mi++)
            af[mi] = *(const short8x*)(&As[p][0] + (wave_m * 64 + mi * 16 + r15) * 32 + rchunk);
#pragma unroll
        for (int ni = 0; ni < 4; ni++)
            bf[ni] = *(const short8x*)(&Bs[p][0] + (wave_n * 64 + ni * 16 + r15) * 32 + rchunk);
#pragma unroll
        for (int mi = 0; mi < 4; mi++)
#pragma unroll
            for (int ni = 0; ni < 4; ni++)
                acc[mi][ni] = __builtin_amdgcn_mfma_f32_16x16x32_bf16(af[mi], bf[ni], acc[mi][ni], 0, 0, 0);
    }
#undef FFN2A_STAGE

    const int laneh = lane >> 4;
#pragma unroll
    for (int mi = 0; mi < 4; mi++)
#pragma unroll
        for (int ni = 0; ni < 4; ni++)
#pragma unroll
            for (int r = 0; r < 4; r++) {
                int ml = wave_m * 64 + mi * 16 + laneh * 4 + r;
                int s = m0 + ml;
                if (s < count) {
                    int n = n0 + wave_n * 64 + ni * 16 + r15;
                    atomicAdd(final_out + (size_t)tids[ml] * HID + n, acc[mi][ni][r]);
                }
            }
}

extern "C" void kernel_launch(void* const* d_in, const int* in_sizes, int n_in,
                              void* d_out, int out_size, void* d_ws, size_t ws_size,
                              hipStream_t stream) {
    const float* X  = (const float*)d_in[0];
    const float* G  = (const float*)d_in[1];
    const float* w1 = (const float*)d_in[2];
    const float* w2 = (const float*)d_in[3];
    const float* w3 = (const float*)d_in[4];

    float* out = (float*)d_out;
    float* out_final  = out;
    float* out_logits = out + (size_t)NT * HID;
    float* out_sel    = out_logits + (size_t)NT * NE;
    float* out_loss   = out_sel + (size_t)NT * TOPK;

    char* ws = (char*)d_ws;
    int*   counts     = (int*)(ws + 0);
    int*   cursor     = (int*)(ws + 64);
    int*   offsets    = (int*)(ws + 128);
    float* importance = (float*)(ws + 192);
    int*   tile_base  = (int*)(ws + 256);              // 13 ints
    int*   sel_e   = (int*)(ws + 512);
    float* sel_w   = (float*)(ws + 197120);
    int*   tok_ids = (int*)(ws + 393728);
    float* slot_w  = (float*)(ws + 590336);
    unsigned short* wb1 = (unsigned short*)(ws + 786944);
    unsigned short* wb3 = (unsigned short*)(ws + 7078400);
    unsigned short* wb2 = (unsigned short*)(ws + 13369856);
    unsigned short* H   = (unsigned short*)(ws + 19661312);   // 49280 x 256 bf16
    int*  inv3          = (int*)(ws + 44892672);              // NT*3 ints
    const size_t obase  = 45089280;
    unsigned short* Obuf = (unsigned short*)(ws + obase);

    unsigned short* xb = (unsigned short*)d_out;   // dead `final` region until combine

    int nc = 0;
    if      (ws_size >= obase + (size_t)NT * TOPK * 1024 * 2) nc = 1024;
    else if (ws_size >= obase + (size_t)NT * TOPK * 512  * 2) nc = 512;
    else if (ws_size >= obase + (size_t)NT * TOPK * 256  * 2) nc = 256;

    hipMemsetAsync(ws, 0, 320, stream);
    router_cvt_kernel<<<768 + NT / 4, 256, 0, stream>>>(
        X, G, w1, w3, w2, wb1, wb3, wb2, out_logits, out_sel, xb, sel_e, sel_w);
    hist_kernel<<<NT / 256, 256, 0, stream>>>(sel_e, sel_w, counts, importance);
    scan_loss<<<1, 64, 0, stream>>>(counts, cursor, offsets, tile_base, importance, out_loss);
    place_kernel<<<NT / 256, 256, 0, stream>>>(sel_e, sel_w, cursor, tok_ids, slot_w, inv3);
    // max tiles = sum ceil(count_e/128) <= 384 + 12 = 396 -> 400 blocks
    ffn1_kernel<<<dim3(400, 2), 256, 0, stream>>>(xb, wb1, wb3, offsets, tile_base,
                                                  tok_ids, slot_w, H);

    if (nc) {
        const int np = 1024 / nc;
        const int pt_shift = (nc == 1024) ? 8 : (nc == 512 ? 7 : 6);
        for (int p = 0; p < np; p++) {
            ffn2_store<<<dim3(400, nc / 128), 256, 0, stream>>>(
                H, wb2, offsets, tile_base, Obuf, p * nc, nc);
            combine_kernel<<<(NT << pt_shift) / 256, 256, 0, stream>>>(
                Obuf, inv3, out_final, p * nc, pt_shift);
        }
    } else {
        hipMemsetAsync(d_out, 0, (size_t)NT * HID * sizeof(float), stream);
        ffn2_atomic<<<dim3(400, 8), 256, 0, stream>>>(H, wb2, offsets, tile_base,
                                                      tok_ids, out_final);
    }
}